// Round 1
// baseline (752.096 us; speedup 1.0000x reference)
//
#include <hip/hip_runtime.h>

// ---------------- common helpers ----------------
typedef __attribute__((ext_vector_type(8))) short bf16x8;
typedef __attribute__((ext_vector_type(4))) float f32x4;

__device__ __forceinline__ short f2bf(float f) {
    union { float f; unsigned u; } c; c.f = f;
    unsigned r = c.u + 0x7FFFu + ((c.u >> 16) & 1u);
    return (short)(r >> 16);
}
__device__ __forceinline__ float bf2f(short s) {
    union { unsigned u; float f; } c; c.u = ((unsigned)(unsigned short)s) << 16;
    return c.f;
}

#define MFMA(a, b, c) __builtin_amdgcn_mfma_f32_16x16x32_bf16((a), (b), (c), 0, 0, 0)

// ws layout (bytes)
#define WS_QKVWT   0         // bf16 [384][128]
#define WS_PROJWT  98304     // bf16 [128][128]
#define WS_FC1WT   131072    // bf16 [512][128]
#define WS_FC2WT   262144    // bf16 [128][512]
#define WS_PB16    393216    // f32  [4][49][49]
#define WS_COMB    434176    // f32  [64][4][49][49]

// ---------------- K0a: weight transpose + bf16 convert ----------------
__global__ __launch_bounds__(256) void k_prep_w(
    const float* __restrict__ qkv_w, const float* __restrict__ proj_w,
    const float* __restrict__ fc1_w, const float* __restrict__ fc2_w,
    short* __restrict__ qkv_wt, short* __restrict__ proj_wt,
    short* __restrict__ fc1_wt, short* __restrict__ fc2_wt) {
    int id = blockIdx.x * 256 + threadIdx.x;
    if (id < 49152) {                       // qkv_wt[n][k] = qkv_w[k][n], n<384,k<128
        int n = id >> 7, k = id & 127;
        qkv_wt[id] = f2bf(qkv_w[k * 384 + n]);
    } else if (id < 65536) {                // proj_wt[n][k] = proj_w[k][n]
        int i = id - 49152; int n = i >> 7, k = i & 127;
        proj_wt[i] = f2bf(proj_w[k * 128 + n]);
    } else if (id < 131072) {               // fc1_wt[n][k] = fc1_w[k][n], n<512,k<128
        int i = id - 65536; int n = i >> 7, k = i & 127;
        fc1_wt[i] = f2bf(fc1_w[k * 512 + n]);
    } else if (id < 196608) {               // fc2_wt[n][k] = fc2_w[k][n], n<128,k<512
        int i = id - 131072; int n = i >> 9, k = i & 511;
        fc2_wt[i] = f2bf(fc2_w[k * 128 + n]);
    }
}

// ---------------- K0b: relative position bias (16*sigmoid(MLP)) ----------------
__device__ __forceinline__ float rpe_f(float u) {
    float us = u * (2.0f / 9.0f);  // u/(7-1) * 8/(7-1)
    return copysignf(log1pf(fabsf(us)), us) * 0.48089834696298783f; // /ln(8)
}

__global__ __launch_bounds__(256) void k_prep_bias(
    const float* __restrict__ w1, const float* __restrict__ b1,
    const float* __restrict__ w2, float* __restrict__ pb16) {
    __shared__ float bt[169][4];
    int tid = threadIdx.x;
    if (tid < 169) {
        int i = tid / 13, j = tid - 13 * (tid / 13);
        float t0 = rpe_f((float)(j - 6));
        float t1 = rpe_f((float)(i - 6));
        float a0 = 0.f, a1 = 0.f, a2 = 0.f, a3 = 0.f;
        for (int k = 0; k < 512; ++k) {
            float r = fmaxf(t0 * w1[k] + t1 * w1[512 + k] + b1[k], 0.f);
            a0 += r * w2[k * 4 + 0]; a1 += r * w2[k * 4 + 1];
            a2 += r * w2[k * 4 + 2]; a3 += r * w2[k * 4 + 3];
        }
        bt[tid][0] = a0; bt[tid][1] = a1; bt[tid][2] = a2; bt[tid][3] = a3;
    }
    __syncthreads();
    for (int idx = tid; idx < 9604; idx += 256) {
        int h = idx / 2401, pq = idx - 2401 * h;
        int p = pq / 49, q = pq - 49 * p;
        int dx = p % 7 - q % 7;     // x-channel of rel index
        int dy = p / 7 - q / 7;
        int m = (dx + 6) * 13 + (dy + 6);
        float v = bt[m][h];
        pb16[idx] = 16.0f / (1.0f + expf(-v));
    }
}

// ---------------- K0c: combined[w][h][p][q] = mask[w][p][q] + pb16[h][p][q] ----------------
__global__ __launch_bounds__(256) void k_combine(
    const float* __restrict__ mask, const float* __restrict__ pb16,
    float* __restrict__ comb) {
    int idx = blockIdx.x * 256 + threadIdx.x;
    if (idx >= 614656) return;
    int w = idx / 9604, rem = idx - 9604 * w;
    int pq = rem % 2401;
    comb[idx] = mask[w * 2401 + pq] + pb16[rem];
}

// ---------------- K1: fused windowed attention block ----------------
// LDS map (shorts):
//   q_s  @0     : [4][49][40]  (head stride 1960) ; aliased by xw and later by ao
//   k_s  @7840  : [4][49][40]
//   v_s  @15680 : [4][32][72]  (vT: [head][ch][token], tokens padded to 64)
//   p_s  @24896 : [4 waves][16][72]
//   xw   @0     : [64][136]  (aliases q_s/k_s head0; freed before q/k/v writes)
__global__ __launch_bounds__(256) void k_attn(
    const float* __restrict__ x, const float* __restrict__ comb,
    const short* __restrict__ qkv_wt, const short* __restrict__ proj_wt,
    const float* __restrict__ q_bias, const float* __restrict__ v_bias,
    const float* __restrict__ logit_scale, const float* __restrict__ proj_b,
    const float* __restrict__ n1g, const float* __restrict__ n1b,
    float* __restrict__ out) {
    __shared__ short sm[29504];
    short* q_s = sm;
    short* k_s = sm + 7840;
    short* v_s = sm + 15680;
    short* p_s = sm + 24896;
    short* xw  = sm;  // alias

    const int tid = threadIdx.x;
    const int lane = tid & 63, wv = tid >> 6;
    const int n16 = lane & 15, q4 = lane >> 4;
    const int wb = blockIdx.x;
    const int bb = wb >> 6, widx = wb & 63;
    const int wy = widx >> 3, wx = widx & 7;

    // ---- P0: gather rolled window -> xw bf16 ----
    if (tid < 196) {
        int tok = tid >> 2, part = tid & 3;
        int ty = tok / 7, tx = tok - 7 * ty;
        int sy = wy * 7 + ty + 3; if (sy >= 56) sy -= 56;
        int sx = wx * 7 + tx + 3; if (sx >= 56) sx -= 56;
        const float* src = x + (((bb * 56 + sy) * 56 + sx) << 7) + part * 32;
        short* dst = xw + tok * 136 + part * 32;
#pragma unroll
        for (int j = 0; j < 8; ++j) {
            float4 v = *(const float4*)(src + j * 4);
            short4 o;
            o.x = f2bf(v.x); o.y = f2bf(v.y); o.z = f2bf(v.z); o.w = f2bf(v.w);
            *(short4*)(dst + j * 4) = o;
        }
    }
    __syncthreads();

    // ---- P1: qkv GEMM, accs held in registers (xw is aliased) ----
    bf16x8 afr[4][4];
#pragma unroll
    for (int mt = 0; mt < 4; ++mt)
#pragma unroll
        for (int ks = 0; ks < 4; ++ks)
            afr[mt][ks] = *(const bf16x8*)(xw + (mt * 16 + n16) * 136 + ks * 32 + q4 * 8);

    f32x4 acc[6][4];
#pragma unroll
    for (int ntl = 0; ntl < 6; ++ntl) {
        int n = (wv * 6 + ntl) * 16 + n16;
        bf16x8 bfr[4];
#pragma unroll
        for (int ks = 0; ks < 4; ++ks)
            bfr[ks] = *(const bf16x8*)(qkv_wt + n * 128 + ks * 32 + q4 * 8);
#pragma unroll
        for (int mt = 0; mt < 4; ++mt) {
            f32x4 a = {0.f, 0.f, 0.f, 0.f};
#pragma unroll
            for (int ks = 0; ks < 4; ++ks) a = MFMA(afr[mt][ks], bfr[ks], a);
            acc[ntl][mt] = a;
        }
    }
    __syncthreads();

    // ---- P2: write q/k/vT (bf16). v padded tokens zeroed. ----
#pragma unroll
    for (int ntl = 0; ntl < 6; ++ntl) {
        int n = (wv * 6 + ntl) * 16 + n16;
        int sec = n >> 7, h = (n >> 5) & 3, chn = n & 31;
        float bias = (sec == 0) ? q_bias[n] : ((sec == 2) ? v_bias[n & 127] : 0.f);
#pragma unroll
        for (int mt = 0; mt < 4; ++mt) {
#pragma unroll
            for (int reg = 0; reg < 4; ++reg) {
                int r = mt * 16 + q4 * 4 + reg;
                float val = acc[ntl][mt][reg] + bias;
                if (sec == 2) {
                    v_s[h * 2304 + chn * 72 + r] = (r < 49) ? f2bf(val) : (short)0;
                } else if (r < 49) {
                    short* base = sec ? k_s : q_s;
                    base[h * 1960 + r * 40 + chn] = f2bf(val);
                }
            }
        }
    }
    __syncthreads();

    // ---- P3: cosine-normalize q (x scale) and k ----
    for (int i = tid; i < 392; i += 256) {
        int which = (i >= 196) ? 1 : 0;
        int rem = i - which * 196;
        int h = rem / 49, t = rem - 49 * h;
        short* row = (which ? k_s : q_s) + h * 1960 + t * 40;
        float vv[32]; float ss = 0.f;
#pragma unroll
        for (int j = 0; j < 8; ++j) {
            short4 s4 = *(const short4*)(row + j * 4);
            vv[j*4+0] = bf2f(s4.x); vv[j*4+1] = bf2f(s4.y);
            vv[j*4+2] = bf2f(s4.z); vv[j*4+3] = bf2f(s4.w);
            ss += vv[j*4+0]*vv[j*4+0] + vv[j*4+1]*vv[j*4+1]
                + vv[j*4+2]*vv[j*4+2] + vv[j*4+3]*vv[j*4+3];
        }
        float inv = 1.0f / sqrtf(fmaxf(ss, 1e-12f));
        if (!which) inv *= expf(fminf(logit_scale[h], 4.6051702f));
#pragma unroll
        for (int j = 0; j < 8; ++j) {
            short4 o;
            o.x = f2bf(vv[j*4+0]*inv); o.y = f2bf(vv[j*4+1]*inv);
            o.z = f2bf(vv[j*4+2]*inv); o.w = f2bf(vv[j*4+3]*inv);
            *(short4*)(row + j * 4) = o;
        }
    }
    __syncthreads();

    // ---- P4: attention, one head at a time; wave wv owns row strip [wv*16, wv*16+16) ----
    const int rb = wv * 16;
#pragma unroll 1
    for (int h = 0; h < 4; ++h) {
        bf16x8 aq = *(const bf16x8*)(q_s + h * 1960 + (rb + n16) * 40 + q4 * 8);
        f32x4 s[4];
#pragma unroll
        for (int nt = 0; nt < 4; ++nt) {
            bf16x8 bk = *(const bf16x8*)(k_s + h * 1960 + (nt * 16 + n16) * 40 + q4 * 8);
            f32x4 z = {0.f, 0.f, 0.f, 0.f};
            s[nt] = MFMA(aq, bk, z);
        }
        // bias + mask + key padding
#pragma unroll
        for (int nt = 0; nt < 4; ++nt) {
            int c = nt * 16 + n16;
#pragma unroll
            for (int reg = 0; reg < 4; ++reg) {
                int r = rb + q4 * 4 + reg;
                float val;
                if (c < 49) {
                    val = s[nt][reg];
                    if (r < 49) val += comb[((widx * 4 + h) * 49 + r) * 49 + c];
                } else val = -INFINITY;
                s[nt][reg] = val;
            }
        }
        // softmax per row (cols spread over 16 lanes x 4 n-tiles)
#pragma unroll
        for (int reg = 0; reg < 4; ++reg) {
            float m = fmaxf(fmaxf(s[0][reg], s[1][reg]), fmaxf(s[2][reg], s[3][reg]));
#pragma unroll
            for (int d = 1; d < 16; d <<= 1) m = fmaxf(m, __shfl_xor(m, d, 64));
            float e0 = expf(s[0][reg] - m), e1 = expf(s[1][reg] - m);
            float e2 = expf(s[2][reg] - m), e3 = expf(s[3][reg] - m);
            float sum = e0 + e1 + e2 + e3;
#pragma unroll
            for (int d = 1; d < 16; d <<= 1) sum += __shfl_xor(sum, d, 64);
            float inv = 1.0f / sum;
            s[0][reg] = e0 * inv; s[1][reg] = e1 * inv;
            s[2][reg] = e2 * inv; s[3][reg] = e3 * inv;
        }
        // P -> LDS (C-layout to A-layout round trip), wave-private buffer
#pragma unroll
        for (int nt = 0; nt < 4; ++nt)
#pragma unroll
            for (int reg = 0; reg < 4; ++reg)
                p_s[wv * 1152 + (q4 * 4 + reg) * 72 + nt * 16 + n16] = f2bf(s[nt][reg]);

        bf16x8 ap0 = *(const bf16x8*)(p_s + wv * 1152 + n16 * 72 + q4 * 8);
        bf16x8 ap1 = *(const bf16x8*)(p_s + wv * 1152 + n16 * 72 + 32 + q4 * 8);
#pragma unroll
        for (int nt2 = 0; nt2 < 2; ++nt2) {
            bf16x8 bv0 = *(const bf16x8*)(v_s + h * 2304 + (nt2 * 16 + n16) * 72 + q4 * 8);
            bf16x8 bv1 = *(const bf16x8*)(v_s + h * 2304 + (nt2 * 16 + n16) * 72 + 32 + q4 * 8);
            f32x4 z = {0.f, 0.f, 0.f, 0.f};
            f32x4 o = MFMA(ap0, bv0, z);
            o = MFMA(ap1, bv1, o);
#pragma unroll
            for (int reg = 0; reg < 4; ++reg) {
                int r = rb + q4 * 4 + reg;
                if (r < 49)  // ao[h] overwrites dead q_s[h]; strip-local rows only
                    q_s[h * 1960 + r * 40 + nt2 * 16 + n16] = f2bf(o[reg]);
            }
        }
    }
    // no barrier needed: proj A-frags are strip-local rows written by this wave

    // ---- P5: proj GEMM ----
    bf16x8 apj[4];
#pragma unroll
    for (int ks = 0; ks < 4; ++ks)
        apj[ks] = *(const bf16x8*)(q_s + ks * 1960 + (rb + n16) * 40 + q4 * 8);
    f32x4 pacc[8];
#pragma unroll
    for (int nt = 0; nt < 8; ++nt) {
        f32x4 a = {0.f, 0.f, 0.f, 0.f};
#pragma unroll
        for (int ks = 0; ks < 4; ++ks) {
            bf16x8 bp = *(const bf16x8*)(proj_wt + (nt * 16 + n16) * 128 + ks * 32 + q4 * 8);
            a = MFMA(apj[ks], bp, a);
        }
        pacc[nt] = a;
    }

    // ---- P6: +proj_b, LayerNorm, +shortcut, scatter ----
    float pbv[8], gv[8], bvv[8];
#pragma unroll
    for (int nt = 0; nt < 8; ++nt) {
        int c = nt * 16 + n16;
        pbv[nt] = proj_b[c]; gv[nt] = n1g[c]; bvv[nt] = n1b[c];
    }
#pragma unroll
    for (int reg = 0; reg < 4; ++reg) {
        int r = rb + q4 * 4 + reg;
        float vals[8]; float s1 = 0.f, s2 = 0.f;
#pragma unroll
        for (int nt = 0; nt < 8; ++nt) {
            float v = pacc[nt][reg] + pbv[nt];
            vals[nt] = v; s1 += v; s2 += v * v;
        }
#pragma unroll
        for (int d = 1; d < 16; d <<= 1) {
            s1 += __shfl_xor(s1, d, 64);
            s2 += __shfl_xor(s2, d, 64);
        }
        float mean = s1 * 0.0078125f;
        float var = s2 * 0.0078125f - mean * mean;
        float inv = 1.0f / sqrtf(var + 1e-3f);
        if (r < 49) {
            int ty = r / 7, tx = r - 7 * ty;
            int fy = wy * 7 + ty + 3; if (fy >= 56) fy -= 56;
            int fx = wx * 7 + tx + 3; if (fx >= 56) fx -= 56;
            int gb = ((bb * 56 + fy) * 56 + fx) << 7;
#pragma unroll
            for (int nt = 0; nt < 8; ++nt) {
                int c = nt * 16 + n16;
                float ln = (vals[nt] - mean) * inv * gv[nt] + bvv[nt];
                out[gb + c] = x[gb + c] + ln;
            }
        }
    }
}

// ---------------- K2: MLP + LN + residual, in-place on d_out ----------------
__global__ __launch_bounds__(256) void k_mlp(
    float* __restrict__ io, const short* __restrict__ fc1_wt,
    const short* __restrict__ fc2_wt, const float* __restrict__ fc1_b,
    const float* __restrict__ fc2_b, const float* __restrict__ n2g,
    const float* __restrict__ n2b) {
    __shared__ short sm2[26624];
    short* xt = sm2;           // [128][136]
    short* hc = sm2 + 17408;   // [128][72]

    const int tid = threadIdx.x;
    const int lane = tid & 63, wv = tid >> 6;
    const int n16 = lane & 15, q4 = lane >> 4;
    const int T0 = blockIdx.x * 128;

    // stage x1 tile -> bf16 LDS
    {
        int trow = tid >> 1, half = tid & 1;
        const float* src = io + (T0 + trow) * 128 + half * 64;
        short* dst = xt + trow * 136 + half * 64;
#pragma unroll
        for (int j = 0; j < 16; ++j) {
            float4 v = *(const float4*)(src + j * 4);
            short4 o;
            o.x = f2bf(v.x); o.y = f2bf(v.y); o.z = f2bf(v.z); o.w = f2bf(v.w);
            *(short4*)(dst + j * 4) = o;
        }
    }
    __syncthreads();

    f32x4 oacc[2][8];
#pragma unroll
    for (int i2 = 0; i2 < 2; ++i2)
#pragma unroll
        for (int nt = 0; nt < 8; ++nt) oacc[i2][nt] = (f32x4){0.f, 0.f, 0.f, 0.f};

#pragma unroll 1
    for (int ch = 0; ch < 8; ++ch) {
        // GEMM1: hidden cols [ch*64 + wv*16, +16), all 8 row-tiles
        int nrow = ch * 64 + wv * 16 + n16;
        bf16x8 b1[4];
#pragma unroll
        for (int ks = 0; ks < 4; ++ks)
            b1[ks] = *(const bf16x8*)(fc1_wt + nrow * 128 + ks * 32 + q4 * 8);
        float fb = fc1_b[nrow];
#pragma unroll
        for (int mt = 0; mt < 8; ++mt) {
            f32x4 a = {0.f, 0.f, 0.f, 0.f};
#pragma unroll
            for (int ks = 0; ks < 4; ++ks) {
                bf16x8 af = *(const bf16x8*)(xt + (mt * 16 + n16) * 136 + ks * 32 + q4 * 8);
                a = MFMA(af, b1[ks], a);
            }
#pragma unroll
            for (int reg = 0; reg < 4; ++reg) {
                float v = a[reg] + fb;
                float g = 0.5f * v * (1.0f + erff(v * 0.7071067811865476f));
                hc[(mt * 16 + q4 * 4 + reg) * 72 + wv * 16 + n16] = f2bf(g);
            }
        }
        __syncthreads();
        // GEMM2: wave strips {wv, wv+4}
        bf16x8 a2[2][2];
#pragma unroll
        for (int i2 = 0; i2 < 2; ++i2) {
            int m = (wv + i2 * 4) * 16;
#pragma unroll
            for (int ks2 = 0; ks2 < 2; ++ks2)
                a2[i2][ks2] = *(const bf16x8*)(hc + (m + n16) * 72 + ks2 * 32 + q4 * 8);
        }
#pragma unroll
        for (int nt2 = 0; nt2 < 8; ++nt2) {
#pragma unroll
            for (int ks2 = 0; ks2 < 2; ++ks2) {
                bf16x8 b2 = *(const bf16x8*)(fc2_wt + (nt2 * 16 + n16) * 512 + ch * 64 + ks2 * 32 + q4 * 8);
                oacc[0][nt2] = MFMA(a2[0][ks2], b2, oacc[0][nt2]);
                oacc[1][nt2] = MFMA(a2[1][ks2], b2, oacc[1][nt2]);
            }
        }
        __syncthreads();
    }

    // epilogue: +fc2_b, LN, +x1 residual
    float f2bv[8], g2[8], b2v[8];
#pragma unroll
    for (int nt2 = 0; nt2 < 8; ++nt2) {
        int c = nt2 * 16 + n16;
        f2bv[nt2] = fc2_b[c]; g2[nt2] = n2g[c]; b2v[nt2] = n2b[c];
    }
#pragma unroll
    for (int i2 = 0; i2 < 2; ++i2) {
        int rb2 = (wv + i2 * 4) * 16;
#pragma unroll
        for (int reg = 0; reg < 4; ++reg) {
            int r = rb2 + q4 * 4 + reg;
            float vals[8]; float s1 = 0.f, s2 = 0.f;
#pragma unroll
            for (int nt2 = 0; nt2 < 8; ++nt2) {
                float v = oacc[i2][nt2][reg] + f2bv[nt2];
                vals[nt2] = v; s1 += v; s2 += v * v;
            }
#pragma unroll
            for (int d = 1; d < 16; d <<= 1) {
                s1 += __shfl_xor(s1, d, 64);
                s2 += __shfl_xor(s2, d, 64);
            }
            float mean = s1 * 0.0078125f;
            float var = s2 * 0.0078125f - mean * mean;
            float inv = 1.0f / sqrtf(var + 1e-3f);
            int gb = (T0 + r) * 128;
#pragma unroll
            for (int nt2 = 0; nt2 < 8; ++nt2) {
                int c = nt2 * 16 + n16;
                float ln = (vals[nt2] - mean) * inv * g2[nt2] + b2v[nt2];
                io[gb + c] = io[gb + c] + ln;
            }
        }
    }
}

// ---------------- launcher ----------------
extern "C" void kernel_launch(void* const* d_in, const int* in_sizes, int n_in,
                              void* d_out, int out_size, void* d_ws, size_t ws_size,
                              hipStream_t stream) {
    const float* x      = (const float*)d_in[0];
    const float* mask   = (const float*)d_in[1];
    const float* n1g    = (const float*)d_in[2];
    const float* n1b    = (const float*)d_in[3];
    const float* qkv_w  = (const float*)d_in[4];
    const float* q_bias = (const float*)d_in[5];
    const float* v_bias = (const float*)d_in[6];
    const float* lscale = (const float*)d_in[7];
    const float* rpe_w1 = (const float*)d_in[8];
    const float* rpe_b1 = (const float*)d_in[9];
    const float* rpe_w2 = (const float*)d_in[10];
    const float* proj_w = (const float*)d_in[11];
    const float* proj_b = (const float*)d_in[12];
    const float* n2g    = (const float*)d_in[13];
    const float* n2b    = (const float*)d_in[14];
    const float* fc1_w  = (const float*)d_in[15];
    const float* fc1_b  = (const float*)d_in[16];
    const float* fc2_w  = (const float*)d_in[17];
    const float* fc2_b  = (const float*)d_in[18];

    char* ws = (char*)d_ws;
    short* qkv_wt  = (short*)(ws + WS_QKVWT);
    short* proj_wt = (short*)(ws + WS_PROJWT);
    short* fc1_wt  = (short*)(ws + WS_FC1WT);
    short* fc2_wt  = (short*)(ws + WS_FC2WT);
    float* pb16    = (float*)(ws + WS_PB16);
    float* comb    = (float*)(ws + WS_COMB);
    float* out     = (float*)d_out;

    k_prep_w<<<768, 256, 0, stream>>>(qkv_w, proj_w, fc1_w, fc2_w,
                                      qkv_wt, proj_wt, fc1_wt, fc2_wt);
    k_prep_bias<<<1, 256, 0, stream>>>(rpe_w1, rpe_b1, rpe_w2, pb16);
    k_combine<<<2401, 256, 0, stream>>>(mask, pb16, comb);
    k_attn<<<4096, 256, 0, stream>>>(x, comb, qkv_wt, proj_wt, q_bias, v_bias,
                                     lscale, proj_b, n1g, n1b, out);
    k_mlp<<<1568, 256, 0, stream>>>(out, fc1_wt, fc2_wt, fc1_b, fc2_b, n2g, n2b);
}

// Round 2
// 612.868 us; speedup vs baseline: 1.2272x; 1.2272x over previous
//
#include <hip/hip_runtime.h>
#include <hip/hip_bf16.h>

// ---------------- common helpers ----------------
typedef __attribute__((ext_vector_type(8))) short bf16x8;
typedef __attribute__((ext_vector_type(4))) float f32x4;

__device__ __forceinline__ short f2bf(float f) {
    union { float f; unsigned u; } c; c.f = f;
    unsigned r = c.u + 0x7FFFu + ((c.u >> 16) & 1u);
    return (short)(r >> 16);
}
__device__ __forceinline__ float bf2f(short s) {
    union { unsigned u; float f; } c; c.u = ((unsigned)(unsigned short)s) << 16;
    return c.f;
}
__device__ __forceinline__ unsigned pk2(float a, float b) {
    __hip_bfloat162 h2 = __float22bfloat162_rn(make_float2(a, b));
    union { __hip_bfloat162 h; unsigned u; } c; c.h = h2;
    return c.u;
}

#define MFMA(a, b, c) __builtin_amdgcn_mfma_f32_16x16x32_bf16((a), (b), (c), 0, 0, 0)

// ws layout (bytes)
#define WS_QKVWT   0         // bf16 [384][128]
#define WS_PROJWT  98304     // bf16 [128][128]
#define WS_FC1WT   131072    // bf16 [512][128]
#define WS_FC2WT   262144    // bf16 [128][512]
#define WS_BT16    393216    // f32  [169][4]  (16*sigmoid(mlp) - scale_h - 8)
#define WS_COMB    434176    // f32  [64][4][49][49]

// ---------------- K0a: weight transpose + bf16 convert ----------------
__global__ __launch_bounds__(256) void k_prep_w(
    const float* __restrict__ qkv_w, const float* __restrict__ proj_w,
    const float* __restrict__ fc1_w, const float* __restrict__ fc2_w,
    short* __restrict__ qkv_wt, short* __restrict__ proj_wt,
    short* __restrict__ fc1_wt, short* __restrict__ fc2_wt) {
    int id = blockIdx.x * 256 + threadIdx.x;
    if (id < 49152) {                       // qkv_wt[n][k] = qkv_w[k][n]
        int n = id >> 7, k = id & 127;
        qkv_wt[id] = f2bf(qkv_w[k * 384 + n]);
    } else if (id < 65536) {                // proj_wt[n][k] = proj_w[k][n]
        int i = id - 49152; int n = i >> 7, k = i & 127;
        proj_wt[i] = f2bf(proj_w[k * 128 + n]);
    } else if (id < 131072) {               // fc1_wt[n][k] = fc1_w[k][n]
        int i = id - 65536; int n = i >> 7, k = i & 127;
        fc1_wt[i] = f2bf(fc1_w[k * 512 + n]);
    } else if (id < 196608) {               // fc2_wt[n][k] = fc2_w[k][n]
        int i = id - 131072; int n = i >> 9, k = i & 511;
        fc2_wt[i] = f2bf(fc2_w[k * 128 + n]);
    }
}

// ---------------- K0b: rel-pos bias table, parallel ----------------
__device__ __forceinline__ float rpe_f(float u) {
    float us = u * (2.0f / 9.0f);
    return copysignf(log1pf(fabsf(us)), us) * 0.48089834696298783f;
}

__global__ __launch_bounds__(256) void k_bias_table(
    const float* __restrict__ w1, const float* __restrict__ b1,
    const float* __restrict__ w2, const float* __restrict__ ls,
    float* __restrict__ bt16s) {
    int m = blockIdx.x;
    int i = m / 13, j = m - 13 * i;
    float t0 = rpe_f((float)(j - 6));
    float t1 = rpe_f((float)(i - 6));
    float a0 = 0.f, a1 = 0.f, a2 = 0.f, a3 = 0.f;
    for (int k = threadIdx.x; k < 512; k += 256) {
        float r = fmaxf(t0 * w1[k] + t1 * w1[512 + k] + b1[k], 0.f);
        a0 += r * w2[k * 4 + 0]; a1 += r * w2[k * 4 + 1];
        a2 += r * w2[k * 4 + 2]; a3 += r * w2[k * 4 + 3];
    }
    __shared__ float red[4][4];
#pragma unroll
    for (int d = 1; d < 64; d <<= 1) {
        a0 += __shfl_xor(a0, d, 64); a1 += __shfl_xor(a1, d, 64);
        a2 += __shfl_xor(a2, d, 64); a3 += __shfl_xor(a3, d, 64);
    }
    int wv = threadIdx.x >> 6;
    if ((threadIdx.x & 63) == 0) { red[wv][0] = a0; red[wv][1] = a1; red[wv][2] = a2; red[wv][3] = a3; }
    __syncthreads();
    if (threadIdx.x < 4) {
        int h = threadIdx.x;
        float s = red[0][h] + red[1][h] + red[2][h] + red[3][h];
        float sig = 16.f / (1.f + __expf(-s));
        float sc = __expf(fminf(ls[h], 4.6051702f));
        bt16s[m * 4 + h] = sig - sc - 8.f;   // fold softmax shift (scale+8) in
    }
}

// ---------------- K0c: combined[w][h][p][q] = mask + table ----------------
__global__ __launch_bounds__(256) void k_combine(
    const float* __restrict__ mask, const float* __restrict__ bt16s,
    float* __restrict__ comb) {
    int idx = blockIdx.x * 256 + threadIdx.x;
    if (idx >= 614656) return;
    int w = idx / 9604, rem = idx - 9604 * w;
    int h = rem / 2401, pq = rem - 2401 * h;
    int p = pq / 49, q = pq - 49 * p;
    int dx = p % 7 - q % 7;
    int dy = p / 7 - q / 7;
    int m = (dx + 6) * 13 + (dy + 6);
    comb[idx] = mask[w * 2401 + pq] + bt16s[m * 4 + h];
}

// ---------------- K1: fused windowed attention ----------------
// LDS (shorts), total 26400 = 52.8KB -> 3 blocks/CU:
//   q: [4][49][32] swizzled  @0      (head stride 1568); later reused for attn-out
//   k: [4][49][40]           @6272   (head stride 1960)
//   v: [4][32][64] swizzled  @14112  (head stride 2048), [ch][token]
//   p: [4w][16][64] swizzled @22304  (wave stride 1024)
//   xw alias @0: [64][136]
#define QS_OFF 0
#define KS_OFF 6272
#define VS_OFF 14112
#define PS_OFF 22304
__device__ __forceinline__ int qs_addr(int h, int r, int c) {
    return QS_OFF + h * 1568 + r * 32 + (c ^ (((r >> 1) & 3) << 3));
}
__device__ __forceinline__ int ks_addr(int h, int r, int c) {
    return KS_OFF + h * 1960 + r * 40 + c;
}
__device__ __forceinline__ int vs_addr(int h, int c, int t) {
    return VS_OFF + h * 2048 + c * 64 + (t ^ ((c & 7) << 3));
}
__device__ __forceinline__ int ps_addr(int w, int r, int c) {
    return PS_OFF + w * 1024 + r * 64 + (c ^ ((r & 7) << 3));
}

__global__ __launch_bounds__(256, 3) void k_attn(
    const float* __restrict__ x, const float* __restrict__ comb,
    const short* __restrict__ qkv_wt, const short* __restrict__ proj_wt,
    const float* __restrict__ q_bias, const float* __restrict__ v_bias,
    const float* __restrict__ logit_scale, const float* __restrict__ proj_b,
    const float* __restrict__ n1g, const float* __restrict__ n1b,
    float* __restrict__ out) {
    __shared__ short sm[26400];
    short* xw = sm;  // alias over q (and start of k) region; dead before qkv writes

    const int tid = threadIdx.x;
    const int lane = tid & 63, wv = tid >> 6;
    const int n16 = lane & 15, q4 = lane >> 4;
    const int wb = blockIdx.x;
    const int bb = wb >> 6, widx = wb & 63;
    const int wy = widx >> 3, wx = widx & 7;

    // ---- P0: gather rolled window -> xw bf16 ----
    if (tid < 196) {
        int tok = tid >> 2, part = tid & 3;
        int ty = tok / 7, tx = tok - 7 * ty;
        int sy = wy * 7 + ty + 3; if (sy >= 56) sy -= 56;
        int sx = wx * 7 + tx + 3; if (sx >= 56) sx -= 56;
        const float* src = x + (((bb * 56 + sy) * 56 + sx) << 7) + part * 32;
        short* dst = xw + tok * 136 + part * 32;
#pragma unroll
        for (int j = 0; j < 4; ++j) {
            float4 a = *(const float4*)(src + j * 8);
            float4 b = *(const float4*)(src + j * 8 + 4);
            uint4 o;
            o.x = pk2(a.x, a.y); o.y = pk2(a.z, a.w);
            o.z = pk2(b.x, b.y); o.w = pk2(b.z, b.w);
            *(uint4*)(dst + j * 8) = o;
        }
    }
    __syncthreads();

    // ---- P1: qkv GEMM (accs in registers while xw is live) ----
    bf16x8 afr[4][4];
#pragma unroll
    for (int mt = 0; mt < 4; ++mt)
#pragma unroll
        for (int ks = 0; ks < 4; ++ks)
            afr[mt][ks] = *(const bf16x8*)(xw + (mt * 16 + n16) * 136 + ks * 32 + q4 * 8);

    f32x4 acc[6][4];
#pragma unroll
    for (int ntl = 0; ntl < 6; ++ntl) {
        int n = (wv * 6 + ntl) * 16 + n16;
        bf16x8 bfr[4];
#pragma unroll
        for (int ks = 0; ks < 4; ++ks)
            bfr[ks] = *(const bf16x8*)(qkv_wt + n * 128 + ks * 32 + q4 * 8);
#pragma unroll
        for (int mt = 0; mt < 4; ++mt) {
            f32x4 a = {0.f, 0.f, 0.f, 0.f};
#pragma unroll
            for (int ks = 0; ks < 4; ++ks) a = MFMA(afr[mt][ks], bfr[ks], a);
            acc[ntl][mt] = a;
        }
    }
    __syncthreads();

    // ---- P2: scatter q/k raw rows, v transposed (short4) ----
#pragma unroll
    for (int ntl = 0; ntl < 6; ++ntl) {
        int g = wv * 6 + ntl, sec = g >> 3;
        if (sec == 2) {   // v -> [ch][token]
            int hv = (g >> 1) & 3;
            int c32 = ((g & 1) << 4) + n16;
            float bias = v_bias[(g - 16) * 16 + n16];
#pragma unroll
            for (int mt = 0; mt < 4; ++mt) {
                int t0 = mt * 16 + q4 * 4;
                short4 o;
                o.x = (t0 + 0 < 49) ? f2bf(acc[ntl][mt][0] + bias) : (short)0;
                o.y = (t0 + 1 < 49) ? f2bf(acc[ntl][mt][1] + bias) : (short)0;
                o.z = (t0 + 2 < 49) ? f2bf(acc[ntl][mt][2] + bias) : (short)0;
                o.w = (t0 + 3 < 49) ? f2bf(acc[ntl][mt][3] + bias) : (short)0;
                *(short4*)(sm + vs_addr(hv, c32, t0)) = o;
            }
        } else {          // q or k, row-major
            int h = (g >> 1) & 3;
            int chn = ((g & 1) << 4) + n16;
            float bias = (sec == 0) ? q_bias[g * 16 + n16] : 0.f;
#pragma unroll
            for (int mt = 0; mt < 4; ++mt) {
#pragma unroll
                for (int reg = 0; reg < 4; ++reg) {
                    int r = mt * 16 + q4 * 4 + reg;
                    if (r < 49) {
                        short vb = f2bf(acc[ntl][mt][reg] + bias);
                        sm[sec == 0 ? qs_addr(h, r, chn) : ks_addr(h, r, chn)] = vb;
                    }
                }
            }
        }
    }
    __syncthreads();

    // ---- P3: cosine-normalize q (x scale) and k ----
    for (int i = tid; i < 392; i += 256) {
        int which = (i >= 196) ? 1 : 0;
        int rem = i - 196 * which;
        int h = rem / 49, t = rem - 49 * h;
        float vv[32]; float ss = 0.f;
#pragma unroll
        for (int j = 0; j < 4; ++j) {
            bf16x8 s8 = which ? *(const bf16x8*)(sm + ks_addr(h, t, j * 8))
                              : *(const bf16x8*)(sm + qs_addr(h, t, j * 8));
#pragma unroll
            for (int e = 0; e < 8; ++e) {
                float f = bf2f(s8[e]); vv[j * 8 + e] = f; ss += f * f;
            }
        }
        float inv = __frsqrt_rn(fmaxf(ss, 1e-12f));
        if (!which) inv *= __expf(fminf(logit_scale[h], 4.6051702f));
#pragma unroll
        for (int j = 0; j < 4; ++j) {
            uint4 o;
            o.x = pk2(vv[j*8+0] * inv, vv[j*8+1] * inv);
            o.y = pk2(vv[j*8+2] * inv, vv[j*8+3] * inv);
            o.z = pk2(vv[j*8+4] * inv, vv[j*8+5] * inv);
            o.w = pk2(vv[j*8+6] * inv, vv[j*8+7] * inv);
            if (which) *(uint4*)(sm + ks_addr(h, t, j * 8)) = o;
            else       *(uint4*)(sm + qs_addr(h, t, j * 8)) = o;
        }
    }
    __syncthreads();

    // ---- P4: per-head attention; wave owns row strip [wv*16, +16) ----
    const int rb = wv * 16;
#pragma unroll 1
    for (int h = 0; h < 4; ++h) {
        const float* cb = comb + (widx * 4 + h) * 2401;
        float cbv[4][4];
#pragma unroll
        for (int nt = 0; nt < 4; ++nt) {
            int c = nt * 16 + n16;
#pragma unroll
            for (int reg = 0; reg < 4; ++reg) {
                int r = rb + q4 * 4 + reg;
                cbv[nt][reg] = (r < 49 && c < 49) ? cb[r * 49 + c] : 0.f;
            }
        }
        bf16x8 aq = *(const bf16x8*)(sm + qs_addr(h, rb + n16, q4 * 8));
        f32x4 s[4];
#pragma unroll
        for (int nt = 0; nt < 4; ++nt) {
            bf16x8 bk = *(const bf16x8*)(sm + ks_addr(h, nt * 16 + n16, q4 * 8));
            f32x4 z = {0.f, 0.f, 0.f, 0.f};
            s[nt] = MFMA(aq, bk, z);
        }
        // exp (no max pass: args bounded by folded -(scale+8) shift)
#pragma unroll
        for (int nt = 0; nt < 4; ++nt) {
            int c = nt * 16 + n16;
#pragma unroll
            for (int reg = 0; reg < 4; ++reg) {
                int r = rb + q4 * 4 + reg;
                s[nt][reg] = (r < 49 && c < 49) ? __expf(s[nt][reg] + cbv[nt][reg]) : 0.f;
            }
        }
        float invr[4];
#pragma unroll
        for (int reg = 0; reg < 4; ++reg) {
            float t = s[0][reg] + s[1][reg] + s[2][reg] + s[3][reg];
            t += __shfl_xor(t, 1, 64); t += __shfl_xor(t, 2, 64);
            t += __shfl_xor(t, 4, 64); t += __shfl_xor(t, 8, 64);
            invr[reg] = __builtin_amdgcn_rcpf(t);
        }
        // unnormalized P -> LDS (C->A layout round trip), wave-private
#pragma unroll
        for (int nt = 0; nt < 4; ++nt)
#pragma unroll
            for (int reg = 0; reg < 4; ++reg)
                sm[ps_addr(wv, q4 * 4 + reg, nt * 16 + n16)] = f2bf(s[nt][reg]);

        bf16x8 ap0 = *(const bf16x8*)(sm + ps_addr(wv, n16, q4 * 8));
        bf16x8 ap1 = *(const bf16x8*)(sm + ps_addr(wv, n16, 32 + q4 * 8));
#pragma unroll
        for (int nt2 = 0; nt2 < 2; ++nt2) {
            bf16x8 bv0 = *(const bf16x8*)(sm + vs_addr(h, nt2 * 16 + n16, q4 * 8));
            bf16x8 bv1 = *(const bf16x8*)(sm + vs_addr(h, nt2 * 16 + n16, 32 + q4 * 8));
            f32x4 z = {0.f, 0.f, 0.f, 0.f};
            f32x4 o = MFMA(ap0, bv0, z);
            o = MFMA(ap1, bv1, o);
#pragma unroll
            for (int reg = 0; reg < 4; ++reg) {
                int r = rb + q4 * 4 + reg;
                if (r < 49)   // attn-out overwrites dead q rows (strip-local)
                    sm[qs_addr(h, r, nt2 * 16 + n16)] = f2bf(o[reg] * invr[reg]);
            }
        }
    }
    // no barrier: proj A-frags are strip-local rows written by this wave

    // ---- P5: proj GEMM ----
    bf16x8 apj[4];
#pragma unroll
    for (int ks = 0; ks < 4; ++ks)
        apj[ks] = *(const bf16x8*)(sm + qs_addr(ks, rb + n16, q4 * 8));
    f32x4 pacc[8];
#pragma unroll
    for (int nt = 0; nt < 8; ++nt) {
        f32x4 a = {0.f, 0.f, 0.f, 0.f};
#pragma unroll
        for (int ks = 0; ks < 4; ++ks) {
            bf16x8 bp = *(const bf16x8*)(proj_wt + (nt * 16 + n16) * 128 + ks * 32 + q4 * 8);
            a = MFMA(apj[ks], bp, a);
        }
        pacc[nt] = a;
    }

    // ---- P6: +proj_b, LayerNorm, +shortcut, scatter ----
    float pbv[8], gv[8], bvv[8];
#pragma unroll
    for (int nt = 0; nt < 8; ++nt) {
        int c = nt * 16 + n16;
        pbv[nt] = proj_b[c]; gv[nt] = n1g[c]; bvv[nt] = n1b[c];
    }
#pragma unroll
    for (int reg = 0; reg < 4; ++reg) {
        int r = rb + q4 * 4 + reg;
        float vals[8]; float s1 = 0.f, s2 = 0.f;
#pragma unroll
        for (int nt = 0; nt < 8; ++nt) {
            float v = pacc[nt][reg] + pbv[nt];
            vals[nt] = v; s1 += v; s2 += v * v;
        }
#pragma unroll
        for (int d = 1; d < 16; d <<= 1) {
            s1 += __shfl_xor(s1, d, 64);
            s2 += __shfl_xor(s2, d, 64);
        }
        float mean = s1 * 0.0078125f;
        float var = s2 * 0.0078125f - mean * mean;
        float inv = __frsqrt_rn(var + 1e-3f);
        if (r < 49) {
            int ty = r / 7, tx = r - 7 * ty;
            int fy = wy * 7 + ty + 3; if (fy >= 56) fy -= 56;
            int fx = wx * 7 + tx + 3; if (fx >= 56) fx -= 56;
            int gb = ((bb * 56 + fy) * 56 + fx) << 7;
#pragma unroll
            for (int nt = 0; nt < 8; ++nt) {
                int c = nt * 16 + n16;
                float ln = (vals[nt] - mean) * inv * gv[nt] + bvv[nt];
                out[gb + c] = x[gb + c] + ln;
            }
        }
    }
}

// ---------------- K2: MLP + LN + residual, wave-independent (0 barriers) ----------------
__global__ __launch_bounds__(256, 3) void k_mlp(
    float* __restrict__ io, const short* __restrict__ fc1_wt,
    const short* __restrict__ fc2_wt, const float* __restrict__ fc1_b,
    const float* __restrict__ fc2_b, const float* __restrict__ n2g,
    const float* __restrict__ n2b) {
    __shared__ short sm2[26624];   // xt [128][136] @0 ; hc [4w][32][72] @17408
    const int tid = threadIdx.x;
    const int lane = tid & 63, wv = tid >> 6;
    const int n16 = lane & 15, q4 = lane >> 4;
    const int T0 = blockIdx.x * 128;
    const int rowbase = wv * 32;
    short* xt = sm2;
    short* hcw = sm2 + 17408 + wv * 2304;

    // stage own 32-token strip -> bf16 LDS (wave-private)
    {
        int r = rowbase + (lane >> 1), half = lane & 1;
        const float* src = io + (T0 + r) * 128 + half * 64;
        short* dst = xt + r * 136 + half * 64;
#pragma unroll
        for (int j = 0; j < 8; ++j) {
            float4 a = *(const float4*)(src + j * 8);
            float4 b = *(const float4*)(src + j * 8 + 4);
            uint4 o;
            o.x = pk2(a.x, a.y); o.y = pk2(a.z, a.w);
            o.z = pk2(b.x, b.y); o.w = pk2(b.z, b.w);
            *(uint4*)(dst + j * 8) = o;
        }
    }

    bf16x8 af[2][4];
#pragma unroll
    for (int mt = 0; mt < 2; ++mt)
#pragma unroll
        for (int ks = 0; ks < 4; ++ks)
            af[mt][ks] = *(const bf16x8*)(xt + (rowbase + mt * 16 + n16) * 136 + ks * 32 + q4 * 8);

    f32x4 oacc[2][8];
#pragma unroll
    for (int mt = 0; mt < 2; ++mt)
#pragma unroll
        for (int nt = 0; nt < 8; ++nt) oacc[mt][nt] = (f32x4){0.f, 0.f, 0.f, 0.f};

#pragma unroll 1
    for (int ch = 0; ch < 8; ++ch) {
        // fc1 (64 hidden cols) + gelu(tanh) -> hc[tok][hid]
#pragma unroll
        for (int nt = 0; nt < 4; ++nt) {
            int nrow = ch * 64 + nt * 16 + n16;
            bf16x8 b1v[4];
#pragma unroll
            for (int ks = 0; ks < 4; ++ks)
                b1v[ks] = *(const bf16x8*)(fc1_wt + nrow * 128 + ks * 32 + q4 * 8);
            float fb = fc1_b[nrow];
#pragma unroll
            for (int mt = 0; mt < 2; ++mt) {
                f32x4 a = {0.f, 0.f, 0.f, 0.f};
#pragma unroll
                for (int ks = 0; ks < 4; ++ks) a = MFMA(af[mt][ks], b1v[ks], a);
#pragma unroll
                for (int reg = 0; reg < 4; ++reg) {
                    float v = a[reg] + fb;
                    float u2 = v * (1.5957691216f + 0.0713548162f * v * v);
                    u2 = fminf(fmaxf(u2, -40.f), 40.f);
                    float ex = __expf(u2);
                    float g = v * ex * __builtin_amdgcn_rcpf(ex + 1.f);
                    hcw[(mt * 16 + q4 * 4 + reg) * 72 + nt * 16 + n16] = f2bf(g);
                }
            }
        }
        // fc2 accumulate
        bf16x8 a2[2][2];
#pragma unroll
        for (int mt = 0; mt < 2; ++mt)
#pragma unroll
            for (int kc = 0; kc < 2; ++kc)
                a2[mt][kc] = *(const bf16x8*)(hcw + (mt * 16 + n16) * 72 + kc * 32 + q4 * 8);
#pragma unroll
        for (int nt2 = 0; nt2 < 8; ++nt2) {
#pragma unroll
            for (int kc = 0; kc < 2; ++kc) {
                bf16x8 b2 = *(const bf16x8*)(fc2_wt + (nt2 * 16 + n16) * 512 + ch * 64 + kc * 32 + q4 * 8);
                oacc[0][nt2] = MFMA(a2[0][kc], b2, oacc[0][nt2]);
                oacc[1][nt2] = MFMA(a2[1][kc], b2, oacc[1][nt2]);
            }
        }
    }

    // epilogue: +fc2_b, LN, +x1 residual
    float f2v[8], g2[8], b2v[8];
#pragma unroll
    for (int nt2 = 0; nt2 < 8; ++nt2) {
        int c = nt2 * 16 + n16;
        f2v[nt2] = fc2_b[c]; g2[nt2] = n2g[c]; b2v[nt2] = n2b[c];
    }
#pragma unroll
    for (int mt = 0; mt < 2; ++mt) {
#pragma unroll
        for (int reg = 0; reg < 4; ++reg) {
            int tl = mt * 16 + q4 * 4 + reg;
            float vals[8]; float s1 = 0.f, s2 = 0.f;
#pragma unroll
            for (int nt2 = 0; nt2 < 8; ++nt2) {
                float v = oacc[mt][nt2][reg] + f2v[nt2];
                vals[nt2] = v; s1 += v; s2 += v * v;
            }
#pragma unroll
            for (int d = 1; d < 16; d <<= 1) {
                s1 += __shfl_xor(s1, d, 64);
                s2 += __shfl_xor(s2, d, 64);
            }
            float mean = s1 * 0.0078125f;
            float var = s2 * 0.0078125f - mean * mean;
            float inv = __frsqrt_rn(var + 1e-3f);
            int gb = (T0 + rowbase + tl) * 128;
#pragma unroll
            for (int nt2 = 0; nt2 < 8; ++nt2) {
                int c = nt2 * 16 + n16;
                float ln = (vals[nt2] - mean) * inv * g2[nt2] + b2v[nt2];
                io[gb + c] = io[gb + c] + ln;
            }
        }
    }
}

// ---------------- launcher ----------------
extern "C" void kernel_launch(void* const* d_in, const int* in_sizes, int n_in,
                              void* d_out, int out_size, void* d_ws, size_t ws_size,
                              hipStream_t stream) {
    const float* x      = (const float*)d_in[0];
    const float* mask   = (const float*)d_in[1];
    const float* n1g    = (const float*)d_in[2];
    const float* n1b    = (const float*)d_in[3];
    const float* qkv_w  = (const float*)d_in[4];
    const float* q_bias = (const float*)d_in[5];
    const float* v_bias = (const float*)d_in[6];
    const float* lscale = (const float*)d_in[7];
    const float* rpe_w1 = (const float*)d_in[8];
    const float* rpe_b1 = (const float*)d_in[9];
    const float* rpe_w2 = (const float*)d_in[10];
    const float* proj_w = (const float*)d_in[11];
    const float* proj_b = (const float*)d_in[12];
    const float* n2g    = (const float*)d_in[13];
    const float* n2b    = (const float*)d_in[14];
    const float* fc1_w  = (const float*)d_in[15];
    const float* fc1_b  = (const float*)d_in[16];
    const float* fc2_w  = (const float*)d_in[17];
    const float* fc2_b  = (const float*)d_in[18];

    char* ws = (char*)d_ws;
    short* qkv_wt  = (short*)(ws + WS_QKVWT);
    short* proj_wt = (short*)(ws + WS_PROJWT);
    short* fc1_wt  = (short*)(ws + WS_FC1WT);
    short* fc2_wt  = (short*)(ws + WS_FC2WT);
    float* bt16s   = (float*)(ws + WS_BT16);
    float* comb    = (float*)(ws + WS_COMB);
    float* out     = (float*)d_out;

    k_prep_w<<<768, 256, 0, stream>>>(qkv_w, proj_w, fc1_w, fc2_w,
                                      qkv_wt, proj_wt, fc1_wt, fc2_wt);
    k_bias_table<<<169, 256, 0, stream>>>(rpe_w1, rpe_b1, rpe_w2, lscale, bt16s);
    k_combine<<<2401, 256, 0, stream>>>(mask, bt16s, comb);
    k_attn<<<4096, 256, 0, stream>>>(x, comb, qkv_wt, proj_wt, q_bias, v_bias,
                                     lscale, proj_b, n1g, n1b, out);
    k_mlp<<<1568, 256, 0, stream>>>(out, fc1_wt, fc2_wt, fc1_b, fc2_b, n2g, n2b);
}